// Round 1
// 463.628 us; speedup vs baseline: 3.2713x; 3.2713x over previous
//
#include <hip/hip_runtime.h>
#include <hip/hip_bf16.h>

// HMS2 fused v2: conv1 (3->64, s2) on VALU with W1 in VGPRs; conv2 (64->128, s2)
// as im2col GEMM on mfma_f32_32x32x16_bf16. Channel-split double-pass keeps LDS
// at 37.8 KB -> 4 blocks/CU. W2 pre-transposed+bf16 into workspace.

#define IMG 2304
#define H1  1152
#define H2  576
#define C1  64
#define C2  128
#define TS  8
#define NTB (H2/TS)        // 72
#define C1T 17
#define C1S (C1T*C1T)      // 289
#define IT  35
#define CPAD 40            // s_c1 row stride in bf16 elems (80 B, 16B-aligned, bank-uniform)

typedef __bf16 bf16_t;
typedef __bf16 bf16x8 __attribute__((ext_vector_type(8)));
typedef float  f32x16 __attribute__((ext_vector_type(16)));

// ---- pre-pass: W2 [3][3][64][128] f32 -> W2T[n][p][kykx][ci'] bf16 (147,456 B) ----
__global__ __launch_bounds__(256) void w2_transform(
    const float* __restrict__ W2, bf16_t* __restrict__ W2T)
{
    int idx  = blockIdx.x*256 + threadIdx.x;   // 73728 = 128*2*9*32
    int ci   = idx & 31;
    int t    = idx >> 5;
    int kykx = t % 9;  t /= 9;
    int p    = t & 1;
    int n    = t >> 1;
    W2T[idx] = (bf16_t)W2[(size_t)(kykx*64 + p*32 + ci)*C2 + n];
}

__global__ __launch_bounds__(256, 4) void hms2_fused(
    const int*    __restrict__ img,
    const float*  __restrict__ W1,
    const float*  __restrict__ b1,
    const float*  __restrict__ b2,
    const bf16_t* __restrict__ W2T,
    float*        __restrict__ out)
{
    __shared__ __align__(16) float s_memf[9456];     // 37,824 B total
    float*  s_img = s_memf;                          // 3675 f32 (14,700 B)
    bf16_t* s_c1  = (bf16_t*)(s_memf + 3676);        // 289*40 bf16 (23,120 B), 16B-aligned

    const int tid   = threadIdx.x;
    const int tileY = blockIdx.x / NTB;
    const int tileX = blockIdx.x % NTB;
    const int e0y = tileY*TS, e0x = tileX*TS;
    const int r0  = 2*e0y,    q0  = 2*e0x;
    const int iy0 = 4*e0y,    ix0 = 4*e0x;

    // ---- stage image tile, normalized, zero-padded past image edge ----
    for (int i = tid; i < IT*IT*3; i += 256) {
        int ch = i % 3, pp = i / 3;
        int r = pp / IT, c = pp % IT;
        int gy = iy0 + r, gx = ix0 + c;
        float v = 0.f;
        if (gy < IMG && gx < IMG)
            v = (float)img[((size_t)gy*IMG + gx)*3 + ch] * (1.f/255.f);
        s_img[i] = v;
    }

    // ---- conv2 MFMA identity ----
    const int lane = tid & 63;
    const int cg   = __builtin_amdgcn_readfirstlane(tid >> 6);  // wave -> N-slice
    const int m    = lane & 31;       // A row / B col within frag
    const int kg   = lane >> 5;       // k subgroup (0/1)
    const int h0   = m >> 3, w0 = m & 7;
    // A base byte offsets (ky=kx=0, cil=0): s = 34h + 2w, byte = s*80 + kg*16
    const int aOff0 = (34*h0       + 2*w0)*80 + kg*16;   // mf=0 (sp = m)
    const int aOff1 = (34*(4 + h0) + 2*w0)*80 + kg*16;   // mf=1 (sp = 32+m)
    const bf16_t* bBase = W2T + (size_t)(cg*32 + m)*576 + kg*8;

    f32x16 acc0, acc1;
    #pragma unroll
    for (int r = 0; r < 16; ++r) { acc0[r] = 0.f; acc1[r] = 0.f; }

    const int cc = tid & 31;          // conv1 channel-within-pass (fixed per thread)

    #pragma unroll 1
    for (int p = 0; p < 2; ++p) {
        // W1 taps for this pass's channel into registers (27 coalesced global loads)
        float wr[27];
        #pragma unroll
        for (int k = 0; k < 27; ++k) wr[k] = W1[k*C1 + p*32 + cc];
        float b1v = b1[p*32 + cc];

        __syncthreads();   // p=0: staging done; p=1: conv2-A reads of s_c1 done

        // ---- conv1 pass p: channels [32p, 32p+32) -> s_c1[s*40 + cc] (bf16) ----
        for (int idx = tid; idx < C1S*32; idx += 256) {
            int s = idx >> 5;
            int r = s / C1T, q = s - C1T*r;
            float v = 0.f;
            if (r0 + r < H1 && q0 + q < H1) {
                const float* ip0 = &s_img[((2*r    )*IT + 2*q)*3];
                const float* ip1 = &s_img[((2*r + 1)*IT + 2*q)*3];
                const float* ip2 = &s_img[((2*r + 2)*IT + 2*q)*3];
                float a0 = b1v, a1 = 0.f, a2 = 0.f;
                #pragma unroll
                for (int e = 0; e < 9; ++e) {          // e = kx*3 + ic
                    a0 = fmaf(ip0[e], wr[e],      a0);
                    a1 = fmaf(ip1[e], wr[9 + e],  a1);
                    a2 = fmaf(ip2[e], wr[18 + e], a2);
                }
                v = fmaxf(a0 + a1 + a2, 0.f);
            }
            s_c1[s*CPAD + cc] = (bf16_t)v;
        }
        __syncthreads();

        // ---- conv2 partial-K GEMM: 18 k-steps of 16 ----
        const bf16_t* bP = bBase + p*288;
        #pragma unroll
        for (int t = 0; t < 18; ++t) {
            const int kykx = t >> 1;
            const int cil  = (t & 1)*16;
            const int ky = kykx/3, kx = kykx - 3*ky;
            const int sh = (17*ky + kx)*80 + cil*2;     // byte shift (16B-aligned)
            bf16x8 aF0 = *(const bf16x8*)((const char*)s_c1 + (aOff0 + sh));
            bf16x8 aF1 = *(const bf16x8*)((const char*)s_c1 + (aOff1 + sh));
            bf16x8 bF  = *(const bf16x8*)(bP + (kykx*32 + cil));
            acc0 = __builtin_amdgcn_mfma_f32_32x32x16_bf16(aF0, bF, acc0, 0, 0, 0);
            acc1 = __builtin_amdgcn_mfma_f32_32x32x16_bf16(aF1, bF, acc1, 0, 0, 0);
        }
    }

    // ---- epilogue: bias+ReLU, LDS transpose (reuse s_mem), coalesced NCHW store ----
    __syncthreads();
    {
        float* s_ep = s_memf;                 // 128*67 = 8576 f32 <= 9456
        const int cOut = cg*32 + m;
        const float b2v = b2[cOut];
        #pragma unroll
        for (int r = 0; r < 16; ++r) {
            int row = (r & 3) + 8*(r >> 2) + 4*kg;      // verified 32x32 C/D layout
            s_ep[cOut*67 + row]      = fmaxf(acc0[r] + b2v, 0.f);
            s_ep[cOut*67 + 32 + row] = fmaxf(acc1[r] + b2v, 0.f);
        }
        __syncthreads();
        const int sp = tid & 63;
        const int gy = e0y + (sp >> 3), gx = e0x + (sp & 7);
        #pragma unroll
        for (int j = 0; j < 32; ++j) {
            int c = cg*32 + j;
            out[(size_t)c*(H2*H2) + (size_t)gy*H2 + gx] = s_ep[c*67 + sp];
        }
    }
}

extern "C" void kernel_launch(void* const* d_in, const int* in_sizes, int n_in,
                              void* d_out, int out_size, void* d_ws, size_t ws_size,
                              hipStream_t stream) {
    const int*   img = (const int*)  d_in[0];
    const float* W1  = (const float*)d_in[1];
    const float* b1  = (const float*)d_in[2];
    const float* W2  = (const float*)d_in[3];
    const float* b2  = (const float*)d_in[4];
    float*       out = (float*)d_out;
    bf16_t*      W2T = (bf16_t*)d_ws;          // 147,456 B

    w2_transform<<<dim3(288), dim3(256), 0, stream>>>(W2, W2T);
    hms2_fused<<<dim3(NTB*NTB), dim3(256), 0, stream>>>(img, W1, b1, b2, W2T, out);
}

// Round 3
// 435.969 us; speedup vs baseline: 3.4789x; 1.0634x over previous
//
#include <hip/hip_runtime.h>

// HMS2 fused v4: conv1 AND conv2 on MFMA.
//  conv1: im2col [320 spatial][28K+pad] f16  x  W1T[64ch][32K] f16  (bias via K=27)
//         -> mfma_f32_32x32x16_f16, masked relu store to s_c1 (bf16, swizzled)
//  conv2: im2col GEMM on mfma_f32_32x32x16_bf16, reads swizzled s_c1.
// Swizzle: addr = s*80 + 16*((s>>3)&1)  (ADD into the row's spare 5th 16B group;
// in-row by construction -- v3's XOR variant collided rows 16t+8/16t+9).
// LDS unions: [im2col 25.6K][s_img 14.7K -> s_c1 23.1K] = 48.7KB -> 3 blocks/CU.

#define IMG 2304
#define H1  1152
#define H2  576
#define C1  64
#define C2  128
#define TS  8
#define NTB (H2/TS)        // 72
#define C1T 17
#define IT  35
#define CPAD 40            // row stride (f16/bf16 elems): 80 B, 16B-aligned

typedef __bf16 bf16_t;
typedef __bf16 bf16x8 __attribute__((ext_vector_type(8)));
typedef __bf16 bf16x4 __attribute__((ext_vector_type(4)));
typedef _Float16 f16_t;
typedef _Float16 f16x8 __attribute__((ext_vector_type(8)));
typedef float  f32x16 __attribute__((ext_vector_type(16)));

#define W2T_BYTES (C2*576*2)     // 147456

// ---- W2 [3][3][64][128] f32 -> W2T[n][p][kykx][ci32] bf16 ----
__global__ __launch_bounds__(256) void w2_transform(
    const float* __restrict__ W2, bf16_t* __restrict__ W2T)
{
    int idx  = blockIdx.x*256 + threadIdx.x;   // 73728
    int ci   = idx & 31;
    int t    = idx >> 5;
    int kykx = t % 9;  t /= 9;
    int p    = t & 1;
    int n    = t >> 1;
    W2T[idx] = (bf16_t)W2[(size_t)(kykx*64 + p*32 + ci)*C2 + n];
}

// ---- W1 [27K][64oc] f32 (+b1) -> W1T[oc][32K] f16, K=27 is bias slot ----
__global__ __launch_bounds__(64) void w1_transform(
    const float* __restrict__ W1, const float* __restrict__ b1,
    f16_t* __restrict__ W1T)
{
    int oc = threadIdx.x;
    for (int k = 0; k < 32; ++k) {
        float v = 0.f;
        if (k < 27) v = W1[k*C1 + oc];
        else if (k == 27) v = b1[oc];
        W1T[oc*32 + k] = (f16_t)v;
    }
}

__global__ __launch_bounds__(256, 3) void hms2_fused(
    const int*    __restrict__ img,
    const float*  __restrict__ b2,
    const bf16_t* __restrict__ W2T,
    const f16_t*  __restrict__ W1T,
    float*        __restrict__ out)
{
    __shared__ __align__(16) char s_raw[48720];
    f16_t* s_i2c = (f16_t*)s_raw;                // [320][CPAD] f16  = 25600 B
    float* s_img = (float*)(s_raw + 25600);      // 3675 f32        = 14700 B
    char*  s_c1b = s_raw + 25600;                // [289][CPAD] bf16 = 23120 B (union)
    float* s_ep  = (float*)s_raw;                // 8576 f32 (union, epilogue)

    const int tid   = threadIdx.x;
    const int tileY = blockIdx.x / NTB;
    const int tileX = blockIdx.x % NTB;
    const int e0y = tileY*TS, e0x = tileX*TS;
    const int r0  = 2*e0y,    q0  = 2*e0x;
    const int iy0 = 4*e0y,    ix0 = 4*e0x;

    // ---- stage image tile, normalized, zero-padded past image edge ----
    for (int i = tid; i < IT*IT*3; i += 256) {
        int ch = i % 3, pp = i / 3;
        int r = pp / IT, c = pp % IT;
        int gy = iy0 + r, gx = ix0 + c;
        float v = 0.f;
        if (gy < IMG && gx < IMG)
            v = (float)img[((size_t)gy*IMG + gx)*3 + ch] * (1.f/255.f);
        s_img[i] = v;
    }

    // ---- im2col lane role: fixed k column per thread ----
    const int kcol = tid & 31;
    const int ky_ = kcol/9, krem = kcol - 9*ky_;
    const int kx_ = krem/3, ic_  = krem - 3*kx_;
    const int koff  = ky_*(IT*3) + kx_*3 + ic_;
    const bool kReal = (kcol < 27), kIs27 = (kcol == 27);

    __syncthreads();

    // ---- build im2col: rows 289..319 and k>=28 zeroed; k=27 = 1.0 (bias) ----
    for (int idx = tid; idx < 320*32; idx += 256) {
        int s = idx >> 5;
        f16_t v = (f16_t)0.f;
        if (s < 289) {
            int r = s/17, q = s - 17*r;
            if (kReal)      v = (f16_t)s_img[(2*r*IT + 2*q)*3 + koff];
            else if (kIs27) v = (f16_t)1.f;
        }
        s_i2c[s*CPAD + kcol] = v;
    }

    // ---- MFMA lane identities ----
    const int lane = tid & 63;
    const int m    = lane & 31;
    const int kg   = lane >> 5;
    const int cg   = __builtin_amdgcn_readfirstlane(tid >> 6);

    const int h0  = m >> 3, w0 = m & 7;
    const int s00 = 34*h0 + 2*w0;
    const bf16_t* bBase = W2T + (size_t)(cg*32 + m)*576 + kg*8;

    f32x16 acc0, acc1;
    #pragma unroll
    for (int r = 0; r < 16; ++r) { acc0[r] = 0.f; acc1[r] = 0.f; }

    __syncthreads();

    #pragma unroll 1
    for (int p = 0; p < 2; ++p) {
        // conv1 A-frags: W1T rows = out-channels [32p, 32p+32)
        const f16_t* w1p = W1T + (size_t)(p*32 + m)*32 + kg*8;
        f16x8 wA = *(const f16x8*)(w1p);
        f16x8 wB = *(const f16x8*)(w1p + 16);

        // ---- conv1 GEMM: D[ch][spatial], waves stride spatial frags ----
        for (int sf = cg; sf < 10; sf += 4) {
            const int n0 = sf*32;
            const f16_t* bp = s_i2c + (size_t)(n0 + m)*CPAD + kg*8;
            f16x8 i0 = *(const f16x8*)(bp);
            f16x8 i1 = *(const f16x8*)(bp + 16);
            f32x16 d;
            #pragma unroll
            for (int r = 0; r < 16; ++r) d[r] = 0.f;
            d = __builtin_amdgcn_mfma_f32_32x32x16_f16(wA, i0, d, 0, 0, 0);
            d = __builtin_amdgcn_mfma_f32_32x32x16_f16(wB, i1, d, 0, 0, 0);

            const int s = n0 + m;                 // spatial col owned by this lane
            if (s < 289) {
                int rsp = s/17, qsp = s - 17*rsp;
                bool ok = (r0 + rsp < H1) && (q0 + qsp < H1);
                char* wp = s_c1b + s*80 + (((s>>3)&1)<<4) + kg*8;   // safe ADD swizzle
                #pragma unroll
                for (int g = 0; g < 4; ++g) {     // ch = 8g + 4kg + (0..3)
                    bf16x4 vv;
                    #pragma unroll
                    for (int jj = 0; jj < 4; ++jj) {
                        float x = fmaxf(d[4*g + jj], 0.f);
                        vv[jj] = ok ? (bf16_t)x : (bf16_t)0.f;
                    }
                    *(bf16x4*)(wp + g*16) = vv;
                }
            }
        }
        __syncthreads();

        // ---- conv2 partial-K GEMM (swizzled A reads) ----
        const bf16_t* bP = bBase + p*288;
        #pragma unroll
        for (int kk = 0; kk < 9; ++kk) {
            const int dsh = (kk/3)*17 + (kk - 3*(kk/3));
            const int sA0 = s00 + dsh;
            const int sA1 = sA0 + 136;
            const int a0  = sA0*80 + (((sA0>>3)&1)<<4) + kg*16;    // safe ADD swizzle
            const int a1  = sA1*80 + (((sA1>>3)&1)<<4) + kg*16;
            #pragma unroll
            for (int chh = 0; chh < 2; ++chh) {
                bf16x8 aF0 = *(const bf16x8*)(s_c1b + a0 + chh*32);
                bf16x8 aF1 = *(const bf16x8*)(s_c1b + a1 + chh*32);
                bf16x8 bF  = *(const bf16x8*)(bP + kk*32 + chh*16);
                acc0 = __builtin_amdgcn_mfma_f32_32x32x16_bf16(aF0, bF, acc0, 0, 0, 0);
                acc1 = __builtin_amdgcn_mfma_f32_32x32x16_bf16(aF1, bF, acc1, 0, 0, 0);
            }
        }
        __syncthreads();
    }

    // ---- epilogue: bias+ReLU, LDS transpose, coalesced NCHW store ----
    {
        const int cOut = cg*32 + m;
        const float b2v = b2[cOut];
        #pragma unroll
        for (int r = 0; r < 16; ++r) {
            int row = (r&3) + 8*(r>>2) + 4*kg;    // verified 32x32 C/D layout
            s_ep[cOut*67 + row]      = fmaxf(acc0[r] + b2v, 0.f);
            s_ep[cOut*67 + 32 + row] = fmaxf(acc1[r] + b2v, 0.f);
        }
        __syncthreads();
        const int sp = tid & 63;
        const int gy = e0y + (sp >> 3), gx = e0x + (sp & 7);
        #pragma unroll
        for (int j = 0; j < 32; ++j) {
            int c = cg*32 + j;
            out[(size_t)c*(H2*H2) + (size_t)gy*H2 + gx] = s_ep[c*67 + sp];
        }
    }
}

extern "C" void kernel_launch(void* const* d_in, const int* in_sizes, int n_in,
                              void* d_out, int out_size, void* d_ws, size_t ws_size,
                              hipStream_t stream) {
    const int*   img = (const int*)  d_in[0];
    const float* W1  = (const float*)d_in[1];
    const float* b1  = (const float*)d_in[2];
    const float* W2  = (const float*)d_in[3];
    const float* b2  = (const float*)d_in[4];
    float*       out = (float*)d_out;
    bf16_t*      W2T = (bf16_t*)d_ws;                          // 147456 B
    f16_t*       W1T = (f16_t*)((char*)d_ws + W2T_BYTES);      //   4096 B

    w2_transform<<<dim3(288), dim3(256), 0, stream>>>(W2, W2T);
    w1_transform<<<dim3(1),   dim3(64),  0, stream>>>(W1, b1, W1T);
    hms2_fused<<<dim3(NTB*NTB), dim3(256), 0, stream>>>(img, b2, W2T, W1T, out);
}

// Round 4
// 386.239 us; speedup vs baseline: 3.9268x; 1.1288x over previous
//
#include <hip/hip_runtime.h>

// HMS2 fused v5: conv1+conv2 on MFMA, 64B LDS rows with paired-row 8-group
// rotation swizzle -> 38.1KB LDS -> 4 blocks/CU; W2T relaid for coalesced
// B-loads (two 512B segments per frag instead of 64 scattered lines).
//  swizzle: byte(s,g) = (s>>1)*128 + 16*((g + 4*(s&1) + ((s>>1)&7)) & 7)
//  - aliasing-safe: fixed s maps its 4 groups into a disjoint half of the pair
//  - conv2 A-reads provably conflict-free (octet sweeps all 8 groups)

#define IMG 2304
#define H1  1152
#define H2  576
#define C1  64
#define C2  128
#define TS  8
#define NTB (H2/TS)        // 72
#define C1T 17
#define IT  35

typedef __bf16 bf16_t;
typedef __bf16 bf16x8 __attribute__((ext_vector_type(8)));
typedef __bf16 bf16x4 __attribute__((ext_vector_type(4)));
typedef _Float16 f16_t;
typedef _Float16 f16x8 __attribute__((ext_vector_type(8)));
typedef float  f32x16 __attribute__((ext_vector_type(16)));

#define W2T_BYTES (C2*576*2)     // 147456

// paired-row swizzle: s = logical row (64B payload), g = 16B group 0..3
#define SWZ(s, g) ( (((s)>>1)*128) + (((((g) + (((s)&1)<<2) + (((s)>>1)&7)) & 7)) << 4) )

// ---- W2 [3][3][64][128] f32 -> W2T[plane=(p*9+kykx)*4+oct][n=128][8ci] bf16 ----
// oct = chh*2 + kg; source ci64 = p*32 + chh*16 + kg*8 + e.
__global__ __launch_bounds__(256) void w2_transform(
    const float* __restrict__ W2, bf16_t* __restrict__ W2T)
{
    int idx = blockIdx.x*256 + threadIdx.x;   // 73728
    int e   = idx & 7;
    int t   = idx >> 3;
    int n   = t & 127;  t >>= 7;
    int oct = t & 3;    t >>= 2;
    int kykx= t % 9;
    int p   = t / 9;
    int chh = oct >> 1, kg = oct & 1;
    int ci64 = p*32 + chh*16 + kg*8 + e;
    W2T[idx] = (bf16_t)W2[(size_t)(kykx*64 + ci64)*C2 + n];
}

// ---- W1 [27K][64oc] f32 (+b1) -> W1T[oc][32K] f16, K=27 is bias slot ----
__global__ __launch_bounds__(64) void w1_transform(
    const float* __restrict__ W1, const float* __restrict__ b1,
    f16_t* __restrict__ W1T)
{
    int oc = threadIdx.x;
    for (int k = 0; k < 32; ++k) {
        float v = 0.f;
        if (k < 27) v = W1[k*C1 + oc];
        else if (k == 27) v = b1[oc];
        W1T[oc*32 + k] = (f16_t)v;
    }
}

__global__ __launch_bounds__(256, 4) void hms2_fused(
    const int*    __restrict__ img,
    const float*  __restrict__ b2,
    const bf16_t* __restrict__ W2T,
    const f16_t*  __restrict__ W1T,
    float*        __restrict__ out)
{
    __shared__ __align__(16) char s_raw[39040];
    char*  s_i2cb = s_raw;                      // [320 rows][64B] swz = 20480 B
    float* s_img  = (float*)(s_raw + 20480);    // 3675 f32 = 14700 B (union)
    char*  s_c1b  = s_raw + 20480;              // [289 rows][64B] swz = 18560 B (union)
    float* s_ep   = (float*)s_raw;              // 128*67*4 = 34304 B (union, epilogue)

    const int tid   = threadIdx.x;
    const int tileY = blockIdx.x / NTB;
    const int tileX = blockIdx.x % NTB;
    const int e0y = tileY*TS, e0x = tileX*TS;
    const int r0  = 2*e0y,    q0  = 2*e0x;
    const int iy0 = 4*e0y,    ix0 = 4*e0x;

    // ---- stage image tile, normalized, zero-padded past image edge ----
    for (int i = tid; i < IT*IT*3; i += 256) {
        int ch = i % 3, pp = i / 3;
        int r = pp / IT, c = pp % IT;
        int gy = iy0 + r, gx = ix0 + c;
        float v = 0.f;
        if (gy < IMG && gx < IMG)
            v = (float)img[((size_t)gy*IMG + gx)*3 + ch] * (1.f/255.f);
        s_img[i] = v;
    }

    // ---- im2col lane role: fixed k column per thread ----
    const int kcol = tid & 31;
    const int ky_ = kcol/9, krem = kcol - 9*ky_;
    const int kx_ = krem/3, ic_  = krem - 3*kx_;
    const int koff  = ky_*(IT*3) + kx_*3 + ic_;
    const bool kReal = (kcol < 27), kIs27 = (kcol == 27);

    __syncthreads();

    // ---- build im2col (swizzled): rows 289..319 and k>=28 zero; k=27 = bias 1 ----
    for (int idx = tid; idx < 320*32; idx += 256) {
        int s = idx >> 5;
        f16_t v = (f16_t)0.f;
        if (s < 289) {
            int r = s/17, q = s - 17*r;
            if (kReal)      v = (f16_t)s_img[(2*r*IT + 2*q)*3 + koff];
            else if (kIs27) v = (f16_t)1.f;
        }
        *(f16_t*)(s_i2cb + SWZ(s, kcol>>3) + (kcol&7)*2) = v;
    }

    // ---- MFMA lane identities ----
    const int lane = tid & 63;
    const int m    = lane & 31;
    const int kg   = lane >> 5;
    const int cg   = __builtin_amdgcn_readfirstlane(tid >> 6);

    const int h0  = m >> 3, w0 = m & 7;
    const int s00 = 34*h0 + 2*w0;
    // coalesced B: plane stride 1024 elems; lane offset = n*8, kg selects plane
    const bf16_t* bBase = W2T + (size_t)kg*1024 + (size_t)(cg*32 + m)*8;

    f32x16 acc0, acc1;
    #pragma unroll
    for (int r = 0; r < 16; ++r) { acc0[r] = 0.f; acc1[r] = 0.f; }

    __syncthreads();

    #pragma unroll 1
    for (int p = 0; p < 2; ++p) {
        // conv1 A-frags: W1T rows = out-channels [32p, 32p+32)
        const f16_t* w1p = W1T + (size_t)(p*32 + m)*32 + kg*8;
        f16x8 wA = *(const f16x8*)(w1p);
        f16x8 wB = *(const f16x8*)(w1p + 16);

        // ---- conv1 GEMM: D[ch][spatial], waves stride spatial frags ----
        for (int sf = cg; sf < 10; sf += 4) {
            const int s = sf*32 + m;
            f16x8 i0 = *(const f16x8*)(s_i2cb + SWZ(s, kg));
            f16x8 i1 = *(const f16x8*)(s_i2cb + SWZ(s, kg+2));
            f32x16 d;
            #pragma unroll
            for (int r = 0; r < 16; ++r) d[r] = 0.f;
            d = __builtin_amdgcn_mfma_f32_32x32x16_f16(wA, i0, d, 0, 0, 0);
            d = __builtin_amdgcn_mfma_f32_32x32x16_f16(wB, i1, d, 0, 0, 0);

            if (s < 289) {
                int rsp = s/17, qsp = s - 17*rsp;
                bool ok = (r0 + rsp < H1) && (q0 + qsp < H1);
                #pragma unroll
                for (int g = 0; g < 4; ++g) {     // ch = 8g + 4kg + (0..3)
                    bf16x4 vv;
                    #pragma unroll
                    for (int jj = 0; jj < 4; ++jj) {
                        float x = fmaxf(d[4*g + jj], 0.f);
                        vv[jj] = ok ? (bf16_t)x : (bf16_t)0.f;
                    }
                    *(bf16x4*)(s_c1b + SWZ(s, g) + kg*8) = vv;
                }
            }
        }
        __syncthreads();

        // ---- conv2 partial-K GEMM: conflict-free swizzled A, coalesced B ----
        const bf16_t* bP = bBase + (size_t)p*36*1024;
        #pragma unroll
        for (int kk = 0; kk < 9; ++kk) {
            const int dsh = (kk/3)*17 + (kk - 3*(kk/3));
            const int sA0 = s00 + dsh;
            const int sA1 = sA0 + 136;
            #pragma unroll
            for (int chh = 0; chh < 2; ++chh) {
                bf16x8 aF0 = *(const bf16x8*)(s_c1b + SWZ(sA0, 2*chh + kg));
                bf16x8 aF1 = *(const bf16x8*)(s_c1b + SWZ(sA1, 2*chh + kg));
                bf16x8 bF  = *(const bf16x8*)(bP + (size_t)(kk*4 + chh*2)*1024);
                acc0 = __builtin_amdgcn_mfma_f32_32x32x16_bf16(aF0, bF, acc0, 0, 0, 0);
                acc1 = __builtin_amdgcn_mfma_f32_32x32x16_bf16(aF1, bF, acc1, 0, 0, 0);
            }
        }
        __syncthreads();
    }

    // ---- epilogue: bias+ReLU, LDS transpose, coalesced NCHW store ----
    {
        const int cOut = cg*32 + m;
        const float b2v = b2[cOut];
        #pragma unroll
        for (int r = 0; r < 16; ++r) {
            int row = (r&3) + 8*(r>>2) + 4*kg;    // verified 32x32 C/D layout
            s_ep[cOut*67 + row]      = fmaxf(acc0[r] + b2v, 0.f);
            s_ep[cOut*67 + 32 + row] = fmaxf(acc1[r] + b2v, 0.f);
        }
        __syncthreads();
        const int sp = tid & 63;
        const int gy = e0y + (sp >> 3), gx = e0x + (sp & 7);
        #pragma unroll
        for (int j = 0; j < 32; ++j) {
            int c = cg*32 + j;
            out[(size_t)c*(H2*H2) + (size_t)gy*H2 + gx] = s_ep[c*67 + sp];
        }
    }
}

extern "C" void kernel_launch(void* const* d_in, const int* in_sizes, int n_in,
                              void* d_out, int out_size, void* d_ws, size_t ws_size,
                              hipStream_t stream) {
    const int*   img = (const int*)  d_in[0];
    const float* W1  = (const float*)d_in[1];
    const float* b1  = (const float*)d_in[2];
    const float* W2  = (const float*)d_in[3];
    const float* b2  = (const float*)d_in[4];
    float*       out = (float*)d_out;
    bf16_t*      W2T = (bf16_t*)d_ws;                          // 147456 B
    f16_t*       W1T = (f16_t*)((char*)d_ws + W2T_BYTES);      //   4096 B

    w2_transform<<<dim3(288), dim3(256), 0, stream>>>(W2, W2T);
    w1_transform<<<dim3(1),   dim3(64),  0, stream>>>(W1, b1, W1T);
    hms2_fused<<<dim3(NTB*NTB), dim3(256), 0, stream>>>(img, b2, W2T, W1T, out);
}